// Round 2
// baseline (155.834 us; speedup 1.0000x reference)
//
#include <hip/hip_runtime.h>
#include <cstddef>

// Problem constants: BS=16, Q=900, NC=91, M=1600
#define NROWS 14400   // BS*Q
#define NCLS  91
#define MTGT  1600
#define RPB   8       // rows (pred queries) per block
#define TPB   320     // 5 waves
#define NG    (MTGT / 4)   // 400 float4 column-groups

__global__ __launch_bounds__(TPB) void matcher_cost_kernel(
    const float* __restrict__ logits,  // [NROWS, NCLS]
    const float* __restrict__ boxes,   // [NROWS, 4] cxcywh
    const int*   __restrict__ tids,    // [MTGT]
    const float* __restrict__ tbox,    // [MTGT, 4] cxcywh
    float*       __restrict__ out)     // [NROWS, MTGT]
{
    __shared__ float s_cc[RPB * NCLS];   // focal class cost (+1.0 folded in)
    const int row0 = blockIdx.x * RPB;
    const int t = threadIdx.x;

    // --- Stage 1: per-row focal class cost table (transcendentals once per
    //     (row,class); numerics identical to the passing round-1 version) ---
    for (int i = t; i < RPB * NCLS; i += TPB) {
        const int r = i / NCLS;
        const int c = i - r * NCLS;
        const float x = logits[(size_t)(row0 + r) * NCLS + c];
        const float p = 1.0f / (1.0f + __expf(-x));
        const float omp = 1.0f - p;
        const float neg = 0.75f * p * p * (-log1pf(-p + 1e-8f));
        const float pos = 0.25f * omp * omp * (-logf(p + 1e-8f));
        s_cc[i] = pos - neg + 1.0f;   // fold giou's "+1" (C = l1+cc+1 - inter/uni - uni/ea)
    }

    // --- Stage 2: block's pred rows: raw cxcywh + xyxy + area (9 f/row) ---
    float pcx[RPB], pcy[RPB], pw[RPB], ph[RPB];
    float px0[RPB], py0[RPB], px1[RPB], py1[RPB], pa[RPB];
    const float4* bx4 = reinterpret_cast<const float4*>(boxes);
#pragma unroll
    for (int r = 0; r < RPB; ++r) {
        const float4 p = bx4[row0 + r];   // uniform address -> broadcast load
        pcx[r] = p.x; pcy[r] = p.y; pw[r] = p.z; ph[r] = p.w;
        px0[r] = p.x - 0.5f * p.z;  px1[r] = p.x + 0.5f * p.z;
        py0[r] = p.y - 0.5f * p.w;  py1[r] = p.y + 0.5f * p.w;
        pa[r]  = p.z * p.w;
    }
    __syncthreads();

    const float4* tb4 = reinterpret_cast<const float4*>(tbox);
    const int4*   id4 = reinterpret_cast<const int4*>(tids);

    // --- Stage 3: thread t owns float4 column-groups g = t, t+320 (t<80) ---
    for (int g = t; g < NG; g += TPB) {
        const int4 idv = id4[g];                   // 4 target ids
        const int  id[4] = { idv.x, idv.y, idv.z, idv.w };
        float4 tb[4];
        float tx0[4], ty0[4], tx1[4], ty1[4], ta[4];
#pragma unroll
        for (int j = 0; j < 4; ++j) {
            tb[j] = tb4[g * 4 + j];                // 64B/lane, wave-contiguous 4KB
            tx0[j] = tb[j].x - 0.5f * tb[j].z;  tx1[j] = tb[j].x + 0.5f * tb[j].z;
            ty0[j] = tb[j].y - 0.5f * tb[j].w;  ty1[j] = tb[j].y + 0.5f * tb[j].w;
            ta[j]  = tb[j].z * tb[j].w;
        }
#pragma unroll
        for (int r = 0; r < RPB; ++r) {
            float4 res;
            float resv[4];
#pragma unroll
            for (int j = 0; j < 4; ++j) {
                const float cc = s_cc[r * NCLS + id[j]];   // LDS gather
                const float l1 = fabsf(pcx[r] - tb[j].x) + fabsf(pcy[r] - tb[j].y)
                               + fabsf(pw[r]  - tb[j].z) + fabsf(ph[r]  - tb[j].w);
                const float iw = fminf(px1[r], tx1[j]) - fmaxf(px0[r], tx0[j]);
                const float ih = fminf(py1[r], ty1[j]) - fmaxf(py0[r], ty0[j]);
                const float inter = fmaxf(iw, 0.0f) * fmaxf(ih, 0.0f);
                const float uni = pa[r] + ta[j] - inter;
                const float ew = fmaxf(px1[r], tx1[j]) - fminf(px0[r], tx0[j]);
                const float eh = fmaxf(py1[r], ty1[j]) - fminf(py0[r], ty0[j]);
                const float ea = ew * eh;
                // giou = inter/uni + uni/ea - 1  ->  single rcp:
                const float num  = fmaf(inter, ea, uni * uni);
                const float rden = __builtin_amdgcn_rcpf(uni * ea);
                resv[j] = l1 + cc - num * rden;     // cc already includes +1
            }
            res.x = resv[0]; res.y = resv[1]; res.z = resv[2]; res.w = resv[3];
            *reinterpret_cast<float4*>(&out[(size_t)(row0 + r) * MTGT + g * 4]) = res;
        }
    }
}

extern "C" void kernel_launch(void* const* d_in, const int* in_sizes, int n_in,
                              void* d_out, int out_size, void* d_ws, size_t ws_size,
                              hipStream_t stream) {
    const float* logits = (const float*)d_in[0];
    const float* boxes  = (const float*)d_in[1];
    const int*   tids   = (const int*)d_in[2];
    const float* tbox   = (const float*)d_in[3];
    float* outp = (float*)d_out;

    dim3 grid(NROWS / RPB);   // 1800 blocks
    dim3 block(TPB);          // 320 threads
    hipLaunchKernelGGL(matcher_cost_kernel, grid, block, 0, stream,
                       logits, boxes, tids, tbox, outp);
}

// Round 3
// 130.508 us; speedup vs baseline: 1.1941x; 1.1941x over previous
//
#include <hip/hip_runtime.h>
#include <cstddef>

// Problem constants: BS=16, Q=900, NC=91, M=1600
#define NROWS 14400          // BS*Q
#define NCLS  91
#define MTGT  1600
#define NG    400            // float4 column-groups per row (1600/4)
#define RPT   2              // rows per thread (amortize target loads)
#define TPB   256
#define TBL   (NROWS * NCLS) // 1,310,400 class-cost entries
#define NTHREADS ((NROWS / RPT) * NG)   // 2,880,000
#define PREP_BLOCKS ((TBL + TPB - 1) / TPB)   // 5120
#define PAIR_BLOCKS (NTHREADS / TPB)          // 11250 exact

// ---- Kernel A: focal classification cost table into workspace ----
// cc[row*91 + c] = pos - neg + 1.0   (the +1 folds GIoU's constant:
//   C = l1 + cc + 1 - inter/uni - uni/ea)
__global__ __launch_bounds__(TPB) void prep_kernel(
    const float* __restrict__ logits, float* __restrict__ cc)
{
    const int gid = blockIdx.x * TPB + threadIdx.x;
    if (gid >= TBL) return;
    const float x = logits[gid];
    const float p = 1.0f / (1.0f + __expf(-x));       // sigmoid
    const float omp = 1.0f - p;
    const float neg = 0.75f * p * p * (-log1pf(-p + 1e-8f));
    const float pos = 0.25f * omp * omp * (-logf(p + 1e-8f));
    cc[gid] = pos - neg + 1.0f;
}

// ---- Kernel B: pairwise cost, 1 thread = 2 rows x 4 columns ----
__global__ __launch_bounds__(TPB) void pair_kernel(
    const float* __restrict__ boxes,   // [NROWS,4] cxcywh
    const int*   __restrict__ tids,    // [MTGT]
    const float* __restrict__ tbox,    // [MTGT,4] cxcywh
    const float* __restrict__ cc,      // [NROWS,NCLS] from prep
    float*       __restrict__ out)     // [NROWS,MTGT]
{
    const int gid = blockIdx.x * TPB + threadIdx.x;   // < 2,880,000
    const int rp  = gid / NG;                         // row-pair [0,7200)
    const int g   = gid - rp * NG;                    // col-group [0,400)
    const int row0 = rp * RPT;

    // two pred rows (semi-uniform within a wave -> cache broadcast)
    const float4* bx4 = reinterpret_cast<const float4*>(boxes);
    const float4 pA = bx4[row0];
    const float4 pB = bx4[row0 + 1];
    const float pAx0 = pA.x - 0.5f * pA.z, pAx1 = pA.x + 0.5f * pA.z;
    const float pAy0 = pA.y - 0.5f * pA.w, pAy1 = pA.y + 0.5f * pA.w;
    const float pAa  = pA.z * pA.w;
    const float pBx0 = pB.x - 0.5f * pB.z, pBx1 = pB.x + 0.5f * pB.z;
    const float pBy0 = pB.y - 0.5f * pB.w, pBy1 = pB.y + 0.5f * pB.w;
    const float pBa  = pB.z * pB.w;

    const int4 idv = reinterpret_cast<const int4*>(tids)[g];
    const int ida[4] = { idv.x, idv.y, idv.z, idv.w };
    const float* ccA = cc + (size_t)row0 * NCLS;
    const float* ccB = ccA + NCLS;

    const float4* tb4 = reinterpret_cast<const float4*>(tbox);
    float rA[4], rB[4];
#pragma unroll
    for (int j = 0; j < 4; ++j) {
        const float4 tb = tb4[g * 4 + j];
        const float tx0 = tb.x - 0.5f * tb.z, tx1 = tb.x + 0.5f * tb.z;
        const float ty0 = tb.y - 0.5f * tb.w, ty1 = tb.y + 0.5f * tb.w;
        const float ta  = tb.z * tb.w;
        const float ccj_a = ccA[ida[j]];   // L1/L2 gather (364B row)
        const float ccj_b = ccB[ida[j]];

        // row A
        {
            const float l1 = fabsf(pA.x - tb.x) + fabsf(pA.y - tb.y)
                           + fabsf(pA.z - tb.z) + fabsf(pA.w - tb.w);
            const float iw = fminf(pAx1, tx1) - fmaxf(pAx0, tx0);
            const float ih = fminf(pAy1, ty1) - fmaxf(pAy0, ty0);
            const float inter = fmaxf(iw, 0.0f) * fmaxf(ih, 0.0f);
            const float uni = pAa + ta - inter;
            const float ew = fmaxf(pAx1, tx1) - fminf(pAx0, tx0);
            const float eh = fmaxf(pAy1, ty1) - fminf(pAy0, ty0);
            const float ea = ew * eh;
            const float num  = fmaf(inter, ea, uni * uni);
            const float rden = __builtin_amdgcn_rcpf(uni * ea);
            rA[j] = l1 + ccj_a - num * rden;
        }
        // row B
        {
            const float l1 = fabsf(pB.x - tb.x) + fabsf(pB.y - tb.y)
                           + fabsf(pB.z - tb.z) + fabsf(pB.w - tb.w);
            const float iw = fminf(pBx1, tx1) - fmaxf(pBx0, tx0);
            const float ih = fminf(pBy1, ty1) - fmaxf(pBy0, ty0);
            const float inter = fmaxf(iw, 0.0f) * fmaxf(ih, 0.0f);
            const float uni = pBa + ta - inter;
            const float ew = fmaxf(pBx1, tx1) - fminf(pBx0, tx0);
            const float eh = fmaxf(pBy1, ty1) - fminf(pBy0, ty0);
            const float ea = ew * eh;
            const float num  = fmaf(inter, ea, uni * uni);
            const float rden = __builtin_amdgcn_rcpf(uni * ea);
            rB[j] = l1 + ccj_b - num * rden;
        }
    }

    float4* out4 = reinterpret_cast<float4*>(out);
    const float4 oA = { rA[0], rA[1], rA[2], rA[3] };
    const float4 oB = { rB[0], rB[1], rB[2], rB[3] };
    out4[(size_t)row0 * NG + g]       = oA;   // wave writes contiguous 1KB
    out4[(size_t)(row0 + 1) * NG + g] = oB;
}

extern "C" void kernel_launch(void* const* d_in, const int* in_sizes, int n_in,
                              void* d_out, int out_size, void* d_ws, size_t ws_size,
                              hipStream_t stream) {
    const float* logits = (const float*)d_in[0];
    const float* boxes  = (const float*)d_in[1];
    const int*   tids   = (const int*)d_in[2];
    const float* tbox   = (const float*)d_in[3];
    float* outp = (float*)d_out;
    float* cc   = (float*)d_ws;   // 5,241,600 B class-cost table

    hipLaunchKernelGGL(prep_kernel, dim3(PREP_BLOCKS), dim3(TPB), 0, stream,
                       logits, cc);
    hipLaunchKernelGGL(pair_kernel, dim3(PAIR_BLOCKS), dim3(TPB), 0, stream,
                       boxes, tids, tbox, cc, outp);
}